// Round 9
// baseline (77.072 us; speedup 1.0000x reference)
//
#include <hip/hip_runtime.h>
#include <hip/hip_bf16.h>

// ---------------------------------------------------------------------------
// Adapter: LayerNorm(2048) -> down(64) -> ReLU -> up(2048), 16384 tokens fp32.
// LN folded into down-proj (x read once):
//   down[n] = rstd*( dot(wg[n],x) - mu*s[n] ) + c[n],  wg = bf16(w_down*gamma)
// R9: SPLIT into two dispatches at the 2MB down-activation seam.
//  - down_kernel: R8's staged down phase, ends storing bf16 down[16384][64].
//  - up_kernel: R5's up phase standalone -- NO LDS, NO barriers, reads the
//    L2-hot down tile from global, streams out with f32x4 stores.
//  Per-dispatch rocprof gives the phase breakdown the fused kernel hid.
// ---------------------------------------------------------------------------

typedef __attribute__((ext_vector_type(8))) short short8;   // 8 x bf16
typedef __attribute__((ext_vector_type(4))) float f32x4;

#define D_MODEL 2048
#define BNECK   64
#define EPS     1e-5f

__device__ inline short f2bf(float f) {                     // prep only
    unsigned int u = __builtin_bit_cast(unsigned int, f);
    unsigned int r = (u + 0x7fffu + ((u >> 16) & 1u)) >> 16; // RNE
    return (short)r;
}
__device__ inline float bf2f(short s) {
    unsigned int u = ((unsigned int)(unsigned short)s) << 16;
    return __builtin_bit_cast(float, u);
}
__device__ inline short hbf(float f) {                      // HW RNE cvt
    __hip_bfloat16 h = __float2bfloat16(f);
    return __builtin_bit_cast(short, h);
}

// ---------------------------------------------------------------------------
// Prep. wg_perm slot = (n>>4)*64 + (k>>5): per-wave contiguous 64KB stream.
// Within slot: lane l = ((k>>3)&3)*16 + (n&15), elem e = k&7.
// wup_perm: slot (b16*2+h): lane l -> (d=b16*16+(l&15), kn=h*32+(l>>4)*8+e).
// s[n] = sum_k bf16(wg), c[n] = w_down[n,:].beta + b_down[n].
// ---------------------------------------------------------------------------
__global__ __launch_bounds__(256) void prep_kernel(
    const float* __restrict__ w_down, const float* __restrict__ gamma,
    const float* __restrict__ beta,   const float* __restrict__ b_down,
    const float* __restrict__ w_up,
    short* __restrict__ wg_perm, short* __restrict__ wup_perm,
    float* __restrict__ s_out, float* __restrict__ c_out)
{
    __shared__ float rs[4], rc[4];
    int b = blockIdx.x;
    if (b < BNECK) {
        int n = b, nf = n >> 4;
        float ps = 0.f, pc = 0.f;
        for (int d = threadIdx.x; d < D_MODEL; d += 256) {
            float wv = w_down[n * D_MODEL + d];
            short h  = f2bf(wv * gamma[d]);
            int t = d >> 5, kg = (d >> 3) & 3, e = d & 7;
            int l = kg * 16 + (n & 15);
            wg_perm[(size_t)((nf * 64 + t) * 64 + l) * 8 + e] = h;
            ps += bf2f(h);
            pc  = fmaf(wv, beta[d], pc);
        }
        for (int o = 32; o > 0; o >>= 1) {
            ps += __shfl_down(ps, o, 64);
            pc += __shfl_down(pc, o, 64);
        }
        int wid = threadIdx.x >> 6, lane = threadIdx.x & 63;
        if (lane == 0) { rs[wid] = ps; rc[wid] = pc; }
        __syncthreads();
        if (threadIdx.x == 0) {
            s_out[n] = rs[0] + rs[1] + rs[2] + rs[3];
            c_out[n] = rc[0] + rc[1] + rc[2] + rc[3] + b_down[n];
        }
    } else {
        for (int j = (b - BNECK) * 256 + threadIdx.x; j < D_MODEL * BNECK;
             j += 64 * 256) {
            int d = j >> 6, kn = j & 63;
            int b16 = d >> 4, h2 = kn >> 5, e = kn & 7;
            int l = ((kn >> 3) & 3) * 16 + (d & 15);
            wup_perm[(size_t)((b16 * 2 + h2) * 64 + l) * 8 + e] = f2bf(w_up[j]);
        }
    }
}

// ---------------------------------------------------------------------------
// Kernel A: LN + down-proj + ReLU -> dtile[16384][64] bf16.
// 1024 blocks x 256 threads; block = 16 tokens; wave owns 16 n over full K.
// ---------------------------------------------------------------------------
__global__ __launch_bounds__(256, 4) void down_kernel(
    const float* __restrict__ x,
    const short* __restrict__ wg_perm,
    const float* __restrict__ s_v,  const float* __restrict__ c_v,
    short* __restrict__ dtile)
{
    __shared__ __align__(16) short xlds[16 * 1024];   // 32KB: 16 rows x 1024 bf16
    __shared__ float stats2[16][2];                   // per-token (mu, rstd)

    const int tid  = threadIdx.x;
    const int wid  = tid >> 6;
    const int lane = tid & 63;
    const int r    = lane & 15;
    const int g    = lane >> 4;
    const int row0 = blockIdx.x * 16;
    char* const ldsb = (char*)xlds;

    // staging assignment: row = tid>>4, 64-f32 chunk sj = tid&15
    const int srow = tid >> 4, sj = tid & 15;
    const float* xsrc = x + (size_t)(row0 + srow) * D_MODEL + sj * 64;
    const int wbyte0 = srow * 2048 + sj * 128;
    const int wswz   = ((srow ^ (sj >> 1)) & 7) << 4;     // 2D XOR swizzle

    float ssum = 0.f, ssq = 0.f;

    auto STAGE_HALF = [&](int half) {
        f32x4 v[16];
#pragma unroll
        for (int q = 0; q < 16; ++q)
            v[q] = *(const f32x4*)(xsrc + half * 1024 + q * 4);
#pragma unroll
        for (int q = 0; q < 16; ++q) {
            ssum += (v[q].x + v[q].y) + (v[q].z + v[q].w);
            ssq = fmaf(v[q].x, v[q].x, ssq); ssq = fmaf(v[q].y, v[q].y, ssq);
            ssq = fmaf(v[q].z, v[q].z, ssq); ssq = fmaf(v[q].w, v[q].w, ssq);
        }
#pragma unroll
        for (int i = 0; i < 8; ++i) {
            const f32x4 a = v[2 * i], b = v[2 * i + 1];
            short8 u;
            u[0] = hbf(a.x); u[1] = hbf(a.y); u[2] = hbf(a.z); u[3] = hbf(a.w);
            u[4] = hbf(b.x); u[5] = hbf(b.y); u[6] = hbf(b.z); u[7] = hbf(b.w);
            *(short8*)(ldsb + wbyte0 + ((i * 16) ^ wswz)) = u;
        }
    };

    const short* wbase = wg_perm + (size_t)(wid * 64) * 512 + lane * 8;
    f32x4 accA = (f32x4){0.f, 0.f, 0.f, 0.f};
    f32x4 accB = (f32x4){0.f, 0.f, 0.f, 0.f};

    auto COMPUTE_HALF = [&](int half) {
#pragma unroll 8
        for (int s = 0; s < 32; ++s) {
            int cb = s * 64 + g * 16;
            int ra = r * 2048 + (cb ^ (((r ^ (s >> 2)) & 7) << 4));
            short8 af = *(const short8*)(ldsb + ra);
            short8 w  = *(const short8*)(wbase + (size_t)(half * 32 + s) * 512);
            if (s & 1)
                accB = __builtin_amdgcn_mfma_f32_16x16x32_bf16(af, w, accB, 0, 0, 0);
            else
                accA = __builtin_amdgcn_mfma_f32_16x16x32_bf16(af, w, accA, 0, 0, 0);
        }
    };

    STAGE_HALF(0);
    __syncthreads();
    COMPUTE_HALF(0);
    __syncthreads();
    STAGE_HALF(1);

#pragma unroll
    for (int m = 1; m < 16; m <<= 1) {
        ssum += __shfl_xor(ssum, m, 64);
        ssq  += __shfl_xor(ssq , m, 64);
    }
    float mu   = ssum * (1.f / D_MODEL);
    float rstd = rsqrtf(ssq * (1.f / D_MODEL) - mu * mu + EPS);
    if ((tid & 15) == 0) { stats2[srow][0] = mu; stats2[srow][1] = rstd; }
    __syncthreads();
    COMPUTE_HALF(1);

    f32x4 acc = accA + accB;

    // fix-up + ReLU -> global dtile (token-major [t][n])
    {
        int   n  = wid * 16 + r;
        float sn = s_v[n], cn = c_v[n];
        short* dts = dtile + (size_t)row0 * BNECK + n;
#pragma unroll
        for (int reg = 0; reg < 4; ++reg) {
            int   m = g * 4 + reg;
            float v = fmaf(stats2[m][1], acc[reg] - stats2[m][0] * sn, cn);
            dts[m * BNECK] = hbf(fmaxf(v, 0.f));
        }
    }
}

// ---------------------------------------------------------------------------
// Kernel B: up-proj + bias. 1024 blocks x 256 threads; NO LDS, NO barriers.
// Block = 16 tokens; wave wid does d-frags [wid*32, wid*32+32).
// ---------------------------------------------------------------------------
__global__ __launch_bounds__(256) void up_kernel(
    const short* __restrict__ dtile, const short* __restrict__ wup_perm,
    const float* __restrict__ b_up,  float* __restrict__ out)
{
    const int wid  = threadIdx.x >> 6;
    const int lane = threadIdx.x & 63;
    const int r    = lane & 15;
    const int g    = lane >> 4;
    const int row0 = blockIdx.x * 16;

    // B-frag: col = token r, k = n = g*8+e (bd0: n 0..31, bd1: n 32..63)
    const short* dt = dtile + (size_t)(row0 + r) * BNECK + g * 8;
    short8 bd0 = *(const short8*)(dt);
    short8 bd1 = *(const short8*)(dt + 32);

    const short* wupl = wup_perm + lane * 8;
    float* outr = out + (size_t)(row0 + r) * D_MODEL;

    short8 ua[2], ub[2];
    {
        int b16 = wid * 32;
        ua[0] = *(const short8*)(wupl + (size_t)(b16 * 2 + 0) * 512);
        ub[0] = *(const short8*)(wupl + (size_t)(b16 * 2 + 1) * 512);
    }
#pragma unroll
    for (int i = 0; i < 32; ++i) {
        int cur = i & 1;
        if (i < 31) {
            int b16 = wid * 32 + i + 1;
            ua[cur ^ 1] = *(const short8*)(wupl + (size_t)(b16 * 2 + 0) * 512);
            ub[cur ^ 1] = *(const short8*)(wupl + (size_t)(b16 * 2 + 1) * 512);
        }
        f32x4 o = (f32x4){0.f, 0.f, 0.f, 0.f};
        o = __builtin_amdgcn_mfma_f32_16x16x32_bf16(ua[cur], bd0, o, 0, 0, 0);
        o = __builtin_amdgcn_mfma_f32_16x16x32_bf16(ub[cur], bd1, o, 0, 0, 0);
        int dbase = (wid * 32 + i) * 16;
        f32x4 bu = *(const f32x4*)(b_up + dbase + g * 4);
        *(f32x4*)(outr + dbase + g * 4) = o + bu;
    }
}

extern "C" void kernel_launch(void* const* d_in, const int* in_sizes, int n_in,
                              void* d_out, int out_size, void* d_ws, size_t ws_size,
                              hipStream_t stream) {
    const float* x      = (const float*)d_in[0];
    const float* gamma  = (const float*)d_in[1];
    const float* beta   = (const float*)d_in[2];
    const float* w_down = (const float*)d_in[3];
    const float* b_down = (const float*)d_in[4];
    const float* w_up   = (const float*)d_in[5];
    const float* b_up   = (const float*)d_in[6];
    float* out = (float*)d_out;

    char* ws = (char*)d_ws;
    short* wg_perm  = (short*)ws;                 // 256 KB @ 0
    short* wup_perm = (short*)(ws + 262144);      // 256 KB @ 256K
    float* s_v  = (float*)(ws + 524288);          // 256 B
    float* c_v  = (float*)(ws + 524544);          // 256 B
    short* dtile = (short*)(ws + 525312);         // 2 MB: down[16384][64] bf16

    prep_kernel<<<128, 256, 0, stream>>>(w_down, gamma, beta, b_down, w_up,
                                         wg_perm, wup_perm, s_v, c_v);
    down_kernel<<<1024, 256, 0, stream>>>(x, wg_perm, s_v, c_v, dtile);
    up_kernel<<<1024, 256, 0, stream>>>(dtile, wup_perm, b_up, out);
}